// Round 9
// baseline (193.996 us; speedup 1.0000x reference)
//
#include <hip/hip_runtime.h>
#include <hip/hip_bf16.h>
#include <math.h>

#define NROWS 8192
#define DIM   768
#define NKC   (DIM / 128)        // 6 k-chunks of 128
#define FCH   16384              // fp8 chunk: 128 rows x 128 cols = 16 KB
#define FPAN  (NKC * FCH)        // fp8 panel: 128 rows x 768 = 98304 B
#define NT128 (NROWS / 128)      // 64 row-blocks
#define NTILES (NT128 * (NT128 + 1) / 2)   // 2080 upper-tri tiles
#define PACK8B ((size_t)NT128 * FPAN)      // 6.29 MB
#define UNITY 0x7F7F7F7F         // E8M0 exponent 127 = 2^0 in every byte

typedef __attribute__((ext_vector_type(4))) float  f32x4;
typedef __attribute__((ext_vector_type(8))) __bf16 bf16x8;
typedef __attribute__((ext_vector_type(4))) __bf16 bf16x4;
typedef __attribute__((ext_vector_type(4))) int    i32x4;
typedef __attribute__((ext_vector_type(8))) int    i32x8;

__device__ __forceinline__ void gload_lds16(const void* g, void* l) {
  __builtin_amdgcn_global_load_lds(
      (const __attribute__((address_space(1))) void*)g,
      (__attribute__((address_space(3))) void*)l, 16, 0, 0);
}

// ---------------------------------------------------------------------------
// Kernel A: fused fp8-pack + prep. One wave per row. f32 -> exact f32 sq-norm
// AND fp8 e4m3 conversion (HW v_cvt_pk_fp8_f32) into K=128 chunk layout with
// the LDS swizzle PRE-APPLIED:
//   chunk(rb, kc) = 128 rows x 128 k-bytes; element (r,c) at byte
//   (r*128 + c) ^ ((r&7)<<4).
// 4B stores have c%16 in {0,4,8,12} and the XOR touches bit 4 only -> each
// store stays inside one 16B granule: relocation-safe.
// ---------------------------------------------------------------------------
__global__ __launch_bounds__(256) void koleo_pack8(const float* __restrict__ X,
                                                   float* __restrict__ sq,
                                                   unsigned int* __restrict__ minbits,
                                                   char* __restrict__ xbf) {
  const int row  = blockIdx.x * 4 + (threadIdx.x >> 6);
  const int lane = threadIdx.x & 63;
  const int rb = row >> 7, r = row & 127;
  const float* xr = X + (size_t)row * DIM;
  float s = 0.f;
#pragma unroll
  for (int i = 0; i < 3; ++i) {            // 768 = 3 * 64 lanes * 4 floats
    const int c0 = lane * 4 + i * 256;
    f32x4 v = *(const f32x4*)(xr + c0);
    s += v.x * v.x + v.y * v.y + v.z * v.z + v.w * v.w;
    int pk = __builtin_amdgcn_cvt_pk_fp8_f32(v.x, v.y, 0, false);
    pk     = __builtin_amdgcn_cvt_pk_fp8_f32(v.z, v.w, pk, true);
    const int kc = c0 >> 7;                // chunk index 0..5
    const int c  = c0 & 127;               // k within chunk
    const int off = (r * 128 + c) ^ ((r & 7) << 4);
    *(int*)(xbf + (size_t)rb * FPAN + (size_t)kc * FCH + off) = pk;
  }
#pragma unroll
  for (int m = 32; m >= 1; m >>= 1) s += __shfl_xor(s, m, 64);
  if (lane == 0) {
    sq[row]      = s;
    minbits[row] = 0x7F800000u;            // +inf
  }
}

// ---------------------------------------------------------------------------
// Kernel B: 128x128 upper-triangular Gram tiles, MX-scaled fp8 K=128 MFMA
// (unity scales). 2-phase double-buffered loop (validated R4/R6/R7): issue
// next chunk's 8 global_load_lds first, then 16x ds_read_b128 frags + 16
// mfma_scale, then vmcnt(0) + one barrier. 6 K-steps.
// LDS: 2 x (A 16KB + B 16KB) = 64 KB dynamic -> 2 blocks/CU.
// Fragments: lane holds rows (m*16 + lane&15), k = (lane>>4)*32 .. +31, read
// as TWO separately-swizzled b128s (granules intact; k-order row-independent
// and identical for A/B -> any k-permutation cancels in the dot product;
// unity scales make scale-block mapping irrelevant).
// Tile ordering = L2-locality segments (validated R6).
// ---------------------------------------------------------------------------
__global__ __launch_bounds__(256, 2) void koleo_tile8m(const char* __restrict__ xbf,
                                                       const float* __restrict__ sq,
                                                       unsigned int* __restrict__ minbits) {
  extern __shared__ char lds[];            // 65536 bytes

  // segment-ordered tile map
  const int b = blockIdx.x;
  int ti, tj;
  if (b < 528) {                           // T0: panels [0,32)
    int rem = b, rl = 32; ti = 0;
    while (rem >= rl) { rem -= rl; ++ti; --rl; }
    tj = ti + rem;
  } else if (b < 1552) {                   // rect bands ti:[0,32) x tj:[32+8q,40+8q)
    const int q = (b - 528) >> 8, rr = (b - 528) & 255;
    ti = rr >> 3; tj = 32 + q * 8 + (rr & 7);
  } else {                                 // T1: panels [32,64)
    int rem = b - 1552, rl = 32; ti = 32;
    while (rem >= rl) { rem -= rl; ++ti; --rl; }
    tj = ti + rem;
  }
  const int i0 = ti * 128, j0 = tj * 128;

  const int tid  = threadIdx.x;
  const int lane = tid & 63;
  const int wave = tid >> 6;               // 0..3
  const int wr   = wave >> 1;              // row half
  const int wc   = wave & 1;               // col half
  const int gb   = (lane >> 4) * 32;       // k-group byte offset within row

  const char* pA = xbf + (size_t)ti * FPAN + wave * 4096 + lane * 16;
  const char* pB = xbf + (size_t)tj * FPAN + wave * 4096 + lane * 16;

  f32x4 acc[4][4] = {};

  // ---- prologue: stage K-chunk 0 into buffer 0 ---------------------------
#pragma unroll
  for (int q = 0; q < 4; ++q) {
    gload_lds16(pA + q * 1024, lds +         wave * 4096 + q * 1024);
    gload_lds16(pB + q * 1024, lds + 16384 + wave * 4096 + q * 1024);
  }
  asm volatile("s_waitcnt vmcnt(0)" ::: "memory");
  __builtin_amdgcn_s_barrier();

  // ---- main K-loop: one barrier per K-chunk of 128 -----------------------
  for (int t = 0; t < NKC; ++t) {
    char* buf  = lds + (t & 1) * 32768;
    char* nbuf = lds + ((t + 1) & 1) * 32768;
    const bool more = (t + 1 < NKC);

    if (more) {                            // issue next-chunk staging FIRST
      const char* sA = pA + (size_t)(t + 1) * FCH;
      const char* sB = pB + (size_t)(t + 1) * FCH;
#pragma unroll
      for (int q = 0; q < 4; ++q) {
        gload_lds16(sA + q * 1024, nbuf +         wave * 4096 + q * 1024);
        gload_lds16(sB + q * 1024, nbuf + 16384 + wave * 4096 + q * 1024);
      }
    }

    i32x8 aF[4], bF[4];
#pragma unroll
    for (int m = 0; m < 4; ++m) {
      const int ra = wr * 64 + m * 16 + (lane & 15);
      const int sa = (ra & 7) << 4;
      i32x4 lo = *(const i32x4*)(buf + ((ra * 128 + gb) ^ sa));
      i32x4 hi = *(const i32x4*)(buf + ((ra * 128 + gb + 16) ^ sa));
      aF[m] = __builtin_shufflevector(lo, hi, 0, 1, 2, 3, 4, 5, 6, 7);
      const int rb2 = wc * 64 + m * 16 + (lane & 15);
      const int sb = (rb2 & 7) << 4;
      i32x4 lo2 = *(const i32x4*)(buf + 16384 + ((rb2 * 128 + gb) ^ sb));
      i32x4 hi2 = *(const i32x4*)(buf + 16384 + ((rb2 * 128 + gb + 16) ^ sb));
      bF[m] = __builtin_shufflevector(lo2, hi2, 0, 1, 2, 3, 4, 5, 6, 7);
    }
#pragma unroll
    for (int m = 0; m < 4; ++m)
#pragma unroll
      for (int n = 0; n < 4; ++n)
        acc[m][n] = __builtin_amdgcn_mfma_scale_f32_16x16x128_f8f6f4(
            aF[m], bF[n], acc[m][n],
            0, 0,                     // cbsz = fp8 e4m3, blgp = fp8 e4m3
            0, UNITY,                 // scale A: opsel 0, all bytes 2^0
            0, UNITY);                // scale B: opsel 0, all bytes 2^0

    if (more) asm volatile("s_waitcnt vmcnt(0)" ::: "memory");
    __builtin_amdgcn_s_barrier();
  }

  // ---- epilogue: d2, diagonal mask, row-min + col-min, atomicMin ----------
  // C/D layout (m89; shape-determined, m127/m128): col=lane&15, row=(lane>>4)*4+reg
  const int cg = lane >> 4;
  const int cl = lane & 15;
  float sqj[4], colmin[4];
#pragma unroll
  for (int n = 0; n < 4; ++n) {
    sqj[n]    = sq[j0 + wc * 64 + n * 16 + cl];
    colmin[n] = INFINITY;
  }
#pragma unroll
  for (int m = 0; m < 4; ++m) {
#pragma unroll
    for (int r = 0; r < 4; ++r) {
      const int gi = i0 + wr * 64 + m * 16 + cg * 4 + r;
      const float si = sq[gi];
      float rowmin = INFINITY;
#pragma unroll
      for (int n = 0; n < 4; ++n) {
        const int gj = j0 + wc * 64 + n * 16 + cl;
        float d2 = si + sqj[n] - 2.0f * acc[m][n][r];
        d2 = fmaxf(d2, 0.0f);
        if (gi == gj) d2 = INFINITY;
        rowmin    = fminf(rowmin, d2);
        colmin[n] = fminf(colmin[n], d2);
      }
      rowmin = fminf(rowmin, __shfl_xor(rowmin, 1, 64));
      rowmin = fminf(rowmin, __shfl_xor(rowmin, 2, 64));
      rowmin = fminf(rowmin, __shfl_xor(rowmin, 4, 64));
      rowmin = fminf(rowmin, __shfl_xor(rowmin, 8, 64));
      if (cl == 0)
        atomicMin(minbits + gi, __float_as_uint(rowmin));
    }
  }
  if (ti != tj) {
#pragma unroll
    for (int n = 0; n < 4; ++n) {
      float cm = colmin[n];
      cm = fminf(cm, __shfl_xor(cm, 16, 64));
      cm = fminf(cm, __shfl_xor(cm, 32, 64));
      if (cg == 0)
        atomicMin(minbits + j0 + wc * 64 + n * 16 + cl, __float_as_uint(cm));
    }
  }
}

// ---------------------------------------------------------------------------
// Fallback (ws too small): bf16 f32-load + in-loop cvt staging, 128^2 tiles.
// ---------------------------------------------------------------------------
__global__ __launch_bounds__(256) void koleo_prep_fb(const float* __restrict__ X,
                                                     float* __restrict__ sq,
                                                     unsigned int* __restrict__ minbits) {
  const int row  = blockIdx.x * 4 + (threadIdx.x >> 6);
  const int lane = threadIdx.x & 63;
  const float* xr = X + (size_t)row * DIM;
  float s = 0.f;
#pragma unroll
  for (int i = 0; i < 3; ++i) {
    f32x4 v = *(const f32x4*)(xr + lane * 4 + i * 256);
    s += v.x * v.x + v.y * v.y + v.z * v.z + v.w * v.w;
  }
#pragma unroll
  for (int m = 32; m >= 1; m >>= 1) s += __shfl_xor(s, m, 64);
  if (lane == 0) { sq[row] = s; minbits[row] = 0x7F800000u; }
}

__global__ __launch_bounds__(256) void koleo_tile_fb(const float* __restrict__ X,
                                                     const float* __restrict__ sq,
                                                     unsigned int* __restrict__ minbits) {
  __shared__ __align__(16) char sA[16384];
  __shared__ __align__(16) char sB[16384];
  int rem = blockIdx.x, ti = 0, rowlen = NT128;
  while (rem >= rowlen) { rem -= rowlen; ++ti; --rowlen; }
  const int tj = ti + rem;
  const int i0 = ti * 128, j0 = tj * 128;
  const int tid = threadIdx.x, lane = tid & 63, wave = tid >> 6;
  const int wr = wave >> 1, wc = wave & 1;
  f32x4 acc[4][4] = {};
  for (int k0 = 0; k0 < DIM; k0 += 64) {
    __syncthreads();
#pragma unroll
    for (int it = 0; it < 8; ++it) {
      const int idx = tid + it * 256;
      const int r = idx >> 4, c4 = idx & 15;
      f32x4 va = *(const f32x4*)(X + (size_t)(i0 + r) * DIM + k0 + c4 * 4);
      f32x4 vb = *(const f32x4*)(X + (size_t)(j0 + r) * DIM + k0 + c4 * 4);
      bf16x4 ha, hb;
      ha[0] = (__bf16)va.x; ha[1] = (__bf16)va.y; ha[2] = (__bf16)va.z; ha[3] = (__bf16)va.w;
      hb[0] = (__bf16)vb.x; hb[1] = (__bf16)vb.y; hb[2] = (__bf16)vb.z; hb[3] = (__bf16)vb.w;
      int off = (r * 128 + c4 * 8) ^ ((r & 7) << 4);
      *(bf16x4*)(sA + off) = ha;
      *(bf16x4*)(sB + off) = hb;
    }
    __syncthreads();
#pragma unroll
    for (int ks = 0; ks < 2; ++ks) {
      bf16x8 af[4], bfr[4];
#pragma unroll
      for (int m = 0; m < 4; ++m) {
        const int ra = wr * 64 + m * 16 + (lane & 15);
        af[m]  = *(const bf16x8*)(sA + ((ra * 128 + ks * 64 + (lane >> 4) * 16) ^ ((ra & 7) << 4)));
        const int rb2 = wc * 64 + m * 16 + (lane & 15);
        bfr[m] = *(const bf16x8*)(sB + ((rb2 * 128 + ks * 64 + (lane >> 4) * 16) ^ ((rb2 & 7) << 4)));
      }
#pragma unroll
      for (int m = 0; m < 4; ++m)
#pragma unroll
        for (int n = 0; n < 4; ++n)
          acc[m][n] = __builtin_amdgcn_mfma_f32_16x16x32_bf16(af[m], bfr[n], acc[m][n], 0, 0, 0);
    }
  }
  const int cg = lane >> 4, cl = lane & 15;
  float sqj[4], colmin[4];
#pragma unroll
  for (int n = 0; n < 4; ++n) { sqj[n] = sq[j0 + wc * 64 + n * 16 + cl]; colmin[n] = INFINITY; }
#pragma unroll
  for (int m = 0; m < 4; ++m) {
#pragma unroll
    for (int r = 0; r < 4; ++r) {
      const int gi = i0 + wr * 64 + m * 16 + cg * 4 + r;
      const float si = sq[gi];
      float rowmin = INFINITY;
#pragma unroll
      for (int n = 0; n < 4; ++n) {
        const int gj = j0 + wc * 64 + n * 16 + cl;
        float d2 = si + sqj[n] - 2.0f * acc[m][n][r];
        d2 = fmaxf(d2, 0.0f);
        if (gi == gj) d2 = INFINITY;
        rowmin = fminf(rowmin, d2);
        colmin[n] = fminf(colmin[n], d2);
      }
      rowmin = fminf(rowmin, __shfl_xor(rowmin, 1, 64));
      rowmin = fminf(rowmin, __shfl_xor(rowmin, 2, 64));
      rowmin = fminf(rowmin, __shfl_xor(rowmin, 4, 64));
      rowmin = fminf(rowmin, __shfl_xor(rowmin, 8, 64));
      if (cl == 0) atomicMin(minbits + gi, __float_as_uint(rowmin));
    }
  }
  if (ti != tj) {
#pragma unroll
    for (int n = 0; n < 4; ++n) {
      float cm = colmin[n];
      cm = fminf(cm, __shfl_xor(cm, 16, 64));
      cm = fminf(cm, __shfl_xor(cm, 32, 64));
      if (cg == 0) atomicMin(minbits + j0 + wc * 64 + n * 16 + cl, __float_as_uint(cm));
    }
  }
}

// ---------------------------------------------------------------------------
// Final: loss = -mean(log(sqrt(min_d2) + eps)), single block
// ---------------------------------------------------------------------------
__global__ __launch_bounds__(1024) void koleo_final(const unsigned int* __restrict__ minbits,
                                                    float* __restrict__ out) {
  __shared__ float wsum[16];
  float s = 0.f;
  for (int i = threadIdx.x; i < NROWS; i += 1024) {
    float d2 = __uint_as_float(minbits[i]);
    s += logf(sqrtf(d2) + 1e-8f);
  }
#pragma unroll
  for (int m = 32; m >= 1; m >>= 1) s += __shfl_xor(s, m, 64);
  const int wv = threadIdx.x >> 6, ln = threadIdx.x & 63;
  if (ln == 0) wsum[wv] = s;
  __syncthreads();
  if (wv == 0) {
    float t = (ln < 16) ? wsum[ln] : 0.f;
#pragma unroll
    for (int m = 8; m >= 1; m >>= 1) t += __shfl_xor(t, m, 64);
    if (ln == 0) out[0] = -t / (float)NROWS;
  }
}

// ---------------------------------------------------------------------------
extern "C" void kernel_launch(void* const* d_in, const int* in_sizes, int n_in,
                              void* d_out, int out_size, void* d_ws, size_t ws_size,
                              hipStream_t stream) {
  const float* X = (const float*)d_in[0];
  float* out = (float*)d_out;
  unsigned int* minbits = (unsigned int*)d_ws;                       // 32 KB
  float* sq = (float*)((char*)d_ws + NROWS * sizeof(unsigned int));  // 32 KB
  char* xbf = (char*)d_ws + 65536;                                   // 6.29 MB

  const size_t need = 65536 + PACK8B;
  if (ws_size >= need) {
    koleo_pack8<<<NROWS / 4, 256, 0, stream>>>(X, sq, minbits, xbf);
    koleo_tile8m<<<NTILES, 256, 65536, stream>>>(xbf, sq, minbits);
  } else {
    koleo_prep_fb<<<NROWS / 4, 256, 0, stream>>>(X, sq, minbits);
    koleo_tile_fb<<<NTILES, 256, 0, stream>>>(X, sq, minbits);
  }
  koleo_final<<<1, 1024, 0, stream>>>(minbits, out);
}

// Round 10
// 117.876 us; speedup vs baseline: 1.6458x; 1.6458x over previous
//
#include <hip/hip_runtime.h>
#include <hip/hip_bf16.h>
#include <math.h>

#define NROWS 8192
#define DIM   768
#define NKC   (DIM / 128)        // 6 k-chunks of 128
#define FCH   16384              // fp8 chunk: 128 rows x 128 cols = 16 KB
#define FPAN  (NKC * FCH)        // fp8 panel: 128 rows x 768 = 98304 B
#define NT128 (NROWS / 128)      // 64 row-blocks
#define NTILES (NT128 * (NT128 + 1) / 2)   // 2080 upper-tri tiles
#define PACK8B ((size_t)NT128 * FPAN)      // 6.29 MB
#define UNITY 0x7F7F7F7F         // E8M0 exponent 127 = 2^0 in every byte

typedef __attribute__((ext_vector_type(4))) float  f32x4;
typedef __attribute__((ext_vector_type(8))) __bf16 bf16x8;
typedef __attribute__((ext_vector_type(4))) __bf16 bf16x4;
typedef __attribute__((ext_vector_type(4))) int    i32x4;
typedef __attribute__((ext_vector_type(8))) int    i32x8;

__device__ __forceinline__ void gload_lds16(const void* g, void* l) {
  __builtin_amdgcn_global_load_lds(
      (const __attribute__((address_space(1))) void*)g,
      (__attribute__((address_space(3))) void*)l, 16, 0, 0);
}

// ---------------------------------------------------------------------------
// Kernel A: fused fp8-pack + prep (UNCHANGED from R8/R9 — validated).
// chunk(rb, kc) = 128 rows x 128 k-bytes; element (r,c) at byte
// (r*128 + c) ^ ((r&7)<<4). 4B stores stay inside one 16B granule: safe.
// ---------------------------------------------------------------------------
__global__ __launch_bounds__(256) void koleo_pack8(const float* __restrict__ X,
                                                   float* __restrict__ sq,
                                                   unsigned int* __restrict__ minbits,
                                                   char* __restrict__ xbf) {
  const int row  = blockIdx.x * 4 + (threadIdx.x >> 6);
  const int lane = threadIdx.x & 63;
  const int rb = row >> 7, r = row & 127;
  const float* xr = X + (size_t)row * DIM;
  float s = 0.f;
#pragma unroll
  for (int i = 0; i < 3; ++i) {            // 768 = 3 * 64 lanes * 4 floats
    const int c0 = lane * 4 + i * 256;
    f32x4 v = *(const f32x4*)(xr + c0);
    s += v.x * v.x + v.y * v.y + v.z * v.z + v.w * v.w;
    int pk = __builtin_amdgcn_cvt_pk_fp8_f32(v.x, v.y, 0, false);
    pk     = __builtin_amdgcn_cvt_pk_fp8_f32(v.z, v.w, pk, true);
    const int kc = c0 >> 7;                // chunk index 0..5
    const int c  = c0 & 127;               // k within chunk
    const int off = (r * 128 + c) ^ ((r & 7) << 4);
    *(int*)(xbf + (size_t)rb * FPAN + (size_t)kc * FCH + off) = pk;
  }
#pragma unroll
  for (int m = 32; m >= 1; m >>= 1) s += __shfl_xor(s, m, 64);
  if (lane == 0) {
    sq[row]      = s;
    minbits[row] = 0x7F800000u;            // +inf
  }
}

// ---------------------------------------------------------------------------
// Kernel B: 128x128 upper-triangular Gram tiles, MX-scaled fp8 K=128 MFMA
// (unity scales). 2-phase dbuf loop (validated). SPILL FIX vs R9:
//   - column-pipelined MFMA: aF[4] loaded once per chunk; B columns flow
//     through a 2-octet bcur/bnext pipeline -> max 6 live i32x8 octets
//     (was 8) + acc 64 + addressing ~= 140 regs.
//   - __launch_bounds__(256) without a min-waves clamp.
// LDS: 2 x (A 16KB + B 16KB) = 64 KB dynamic.
// Tile ordering = L2-locality segments (validated R6).
// ---------------------------------------------------------------------------
#define LOADA(mm)                                                             \
  { const int ra = wr * 64 + (mm) * 16 + (lane & 15);                         \
    const int sa = (ra & 7) << 4;                                             \
    i32x4 lo = *(const i32x4*)(buf + ((ra * 128 + gb) ^ sa));                 \
    i32x4 hi = *(const i32x4*)(buf + ((ra * 128 + gb + 16) ^ sa));            \
    aF[mm] = __builtin_shufflevector(lo, hi, 0, 1, 2, 3, 4, 5, 6, 7); }

#define LOADB(dst, nn)                                                        \
  { const int rb2 = wc * 64 + (nn) * 16 + (lane & 15);                        \
    const int sb = (rb2 & 7) << 4;                                            \
    i32x4 lo = *(const i32x4*)(buf + 16384 + ((rb2 * 128 + gb) ^ sb));        \
    i32x4 hi = *(const i32x4*)(buf + 16384 + ((rb2 * 128 + gb + 16) ^ sb));   \
    dst = __builtin_shufflevector(lo, hi, 0, 1, 2, 3, 4, 5, 6, 7); }

__global__ __launch_bounds__(256) void koleo_tile8m(const char* __restrict__ xbf,
                                                    const float* __restrict__ sq,
                                                    unsigned int* __restrict__ minbits) {
  extern __shared__ char lds[];            // 65536 bytes

  // segment-ordered tile map
  const int b = blockIdx.x;
  int ti, tj;
  if (b < 528) {                           // T0: panels [0,32)
    int rem = b, rl = 32; ti = 0;
    while (rem >= rl) { rem -= rl; ++ti; --rl; }
    tj = ti + rem;
  } else if (b < 1552) {                   // rect bands ti:[0,32) x tj:[32+8q,40+8q)
    const int q = (b - 528) >> 8, rr = (b - 528) & 255;
    ti = rr >> 3; tj = 32 + q * 8 + (rr & 7);
  } else {                                 // T1: panels [32,64)
    int rem = b - 1552, rl = 32; ti = 32;
    while (rem >= rl) { rem -= rl; ++ti; --rl; }
    tj = ti + rem;
  }
  const int i0 = ti * 128, j0 = tj * 128;

  const int tid  = threadIdx.x;
  const int lane = tid & 63;
  const int wave = tid >> 6;               // 0..3
  const int wr   = wave >> 1;              // row half
  const int wc   = wave & 1;               // col half
  const int gb   = (lane >> 4) * 32;       // k-group byte offset within row

  const char* pA = xbf + (size_t)ti * FPAN + wave * 4096 + lane * 16;
  const char* pB = xbf + (size_t)tj * FPAN + wave * 4096 + lane * 16;

  f32x4 acc[4][4] = {};

  // ---- prologue: stage K-chunk 0 into buffer 0 ---------------------------
#pragma unroll
  for (int q = 0; q < 4; ++q) {
    gload_lds16(pA + q * 1024, lds +         wave * 4096 + q * 1024);
    gload_lds16(pB + q * 1024, lds + 16384 + wave * 4096 + q * 1024);
  }
  asm volatile("s_waitcnt vmcnt(0)" ::: "memory");
  __builtin_amdgcn_s_barrier();

  // ---- main K-loop: one barrier per K-chunk of 128 -----------------------
  for (int t = 0; t < NKC; ++t) {
    char* buf  = lds + (t & 1) * 32768;
    char* nbuf = lds + ((t + 1) & 1) * 32768;
    const bool more = (t + 1 < NKC);

    if (more) {                            // issue next-chunk staging FIRST
      const char* sA = pA + (size_t)(t + 1) * FCH;
      const char* sB = pB + (size_t)(t + 1) * FCH;
#pragma unroll
      for (int q = 0; q < 4; ++q) {
        gload_lds16(sA + q * 1024, nbuf +         wave * 4096 + q * 1024);
        gload_lds16(sB + q * 1024, nbuf + 16384 + wave * 4096 + q * 1024);
      }
    }

    // A fragments once per chunk (4 octets), B columns pipelined (2 octets)
    i32x8 aF[4], bcur, bnext;
#pragma unroll
    for (int m = 0; m < 4; ++m) LOADA(m);
    LOADB(bcur, 0);
#pragma unroll
    for (int n = 0; n < 4; ++n) {
      if (n < 3) LOADB(bnext, n + 1);
#pragma unroll
      for (int m = 0; m < 4; ++m)
        acc[m][n] = __builtin_amdgcn_mfma_scale_f32_16x16x128_f8f6f4(
            aF[m], bcur, acc[m][n],
            0, 0,                     // cbsz = fp8 e4m3, blgp = fp8 e4m3
            0, UNITY,                 // scale A: opsel 0, all bytes 2^0
            0, UNITY);                // scale B: opsel 0, all bytes 2^0
      bcur = bnext;
    }

    if (more) asm volatile("s_waitcnt vmcnt(0)" ::: "memory");
    __builtin_amdgcn_s_barrier();
  }

  // ---- epilogue: d2, diagonal mask, row-min + col-min, atomicMin ----------
  // C/D layout (m89; shape-determined, m127/m128): col=lane&15, row=(lane>>4)*4+reg
  const int cg = lane >> 4;
  const int cl = lane & 15;
  float sqj[4], colmin[4];
#pragma unroll
  for (int n = 0; n < 4; ++n) {
    sqj[n]    = sq[j0 + wc * 64 + n * 16 + cl];
    colmin[n] = INFINITY;
  }
#pragma unroll
  for (int m = 0; m < 4; ++m) {
#pragma unroll
    for (int r = 0; r < 4; ++r) {
      const int gi = i0 + wr * 64 + m * 16 + cg * 4 + r;
      const float si = sq[gi];
      float rowmin = INFINITY;
#pragma unroll
      for (int n = 0; n < 4; ++n) {
        const int gj = j0 + wc * 64 + n * 16 + cl;
        float d2 = si + sqj[n] - 2.0f * acc[m][n][r];
        d2 = fmaxf(d2, 0.0f);
        if (gi == gj) d2 = INFINITY;
        rowmin    = fminf(rowmin, d2);
        colmin[n] = fminf(colmin[n], d2);
      }
      rowmin = fminf(rowmin, __shfl_xor(rowmin, 1, 64));
      rowmin = fminf(rowmin, __shfl_xor(rowmin, 2, 64));
      rowmin = fminf(rowmin, __shfl_xor(rowmin, 4, 64));
      rowmin = fminf(rowmin, __shfl_xor(rowmin, 8, 64));
      if (cl == 0)
        atomicMin(minbits + gi, __float_as_uint(rowmin));
    }
  }
  if (ti != tj) {
#pragma unroll
    for (int n = 0; n < 4; ++n) {
      float cm = colmin[n];
      cm = fminf(cm, __shfl_xor(cm, 16, 64));
      cm = fminf(cm, __shfl_xor(cm, 32, 64));
      if (cg == 0)
        atomicMin(minbits + j0 + wc * 64 + n * 16 + cl, __float_as_uint(cm));
    }
  }
}

// ---------------------------------------------------------------------------
// Fallback (ws too small): bf16 f32-load + in-loop cvt staging, 128^2 tiles.
// ---------------------------------------------------------------------------
__global__ __launch_bounds__(256) void koleo_prep_fb(const float* __restrict__ X,
                                                     float* __restrict__ sq,
                                                     unsigned int* __restrict__ minbits) {
  const int row  = blockIdx.x * 4 + (threadIdx.x >> 6);
  const int lane = threadIdx.x & 63;
  const float* xr = X + (size_t)row * DIM;
  float s = 0.f;
#pragma unroll
  for (int i = 0; i < 3; ++i) {
    f32x4 v = *(const f32x4*)(xr + lane * 4 + i * 256);
    s += v.x * v.x + v.y * v.y + v.z * v.z + v.w * v.w;
  }
#pragma unroll
  for (int m = 32; m >= 1; m >>= 1) s += __shfl_xor(s, m, 64);
  if (lane == 0) { sq[row] = s; minbits[row] = 0x7F800000u; }
}

__global__ __launch_bounds__(256) void koleo_tile_fb(const float* __restrict__ X,
                                                     const float* __restrict__ sq,
                                                     unsigned int* __restrict__ minbits) {
  __shared__ __align__(16) char sA[16384];
  __shared__ __align__(16) char sB[16384];
  int rem = blockIdx.x, ti = 0, rowlen = NT128;
  while (rem >= rowlen) { rem -= rowlen; ++ti; --rowlen; }
  const int tj = ti + rem;
  const int i0 = ti * 128, j0 = tj * 128;
  const int tid = threadIdx.x, lane = tid & 63, wave = tid >> 6;
  const int wr = wave >> 1, wc = wave & 1;
  f32x4 acc[4][4] = {};
  for (int k0 = 0; k0 < DIM; k0 += 64) {
    __syncthreads();
#pragma unroll
    for (int it = 0; it < 8; ++it) {
      const int idx = tid + it * 256;
      const int r = idx >> 4, c4 = idx & 15;
      f32x4 va = *(const f32x4*)(X + (size_t)(i0 + r) * DIM + k0 + c4 * 4);
      f32x4 vb = *(const f32x4*)(X + (size_t)(j0 + r) * DIM + k0 + c4 * 4);
      bf16x4 ha, hb;
      ha[0] = (__bf16)va.x; ha[1] = (__bf16)va.y; ha[2] = (__bf16)va.z; ha[3] = (__bf16)va.w;
      hb[0] = (__bf16)vb.x; hb[1] = (__bf16)vb.y; hb[2] = (__bf16)vb.z; hb[3] = (__bf16)vb.w;
      int off = (r * 128 + c4 * 8) ^ ((r & 7) << 4);
      *(bf16x4*)(sA + off) = ha;
      *(bf16x4*)(sB + off) = hb;
    }
    __syncthreads();
#pragma unroll
    for (int ks = 0; ks < 2; ++ks) {
      bf16x8 af[4], bfr[4];
#pragma unroll
      for (int m = 0; m < 4; ++m) {
        const int ra = wr * 64 + m * 16 + (lane & 15);
        af[m]  = *(const bf16x8*)(sA + ((ra * 128 + ks * 64 + (lane >> 4) * 16) ^ ((ra & 7) << 4)));
        const int rb2 = wc * 64 + m * 16 + (lane & 15);
        bfr[m] = *(const bf16x8*)(sB + ((rb2 * 128 + ks * 64 + (lane >> 4) * 16) ^ ((rb2 & 7) << 4)));
      }
#pragma unroll
      for (int m = 0; m < 4; ++m)
#pragma unroll
        for (int n = 0; n < 4; ++n)
          acc[m][n] = __builtin_amdgcn_mfma_f32_16x16x32_bf16(af[m], bfr[n], acc[m][n], 0, 0, 0);
    }
  }
  const int cg = lane >> 4, cl = lane & 15;
  float sqj[4], colmin[4];
#pragma unroll
  for (int n = 0; n < 4; ++n) { sqj[n] = sq[j0 + wc * 64 + n * 16 + cl]; colmin[n] = INFINITY; }
#pragma unroll
  for (int m = 0; m < 4; ++m) {
#pragma unroll
    for (int r = 0; r < 4; ++r) {
      const int gi = i0 + wr * 64 + m * 16 + cg * 4 + r;
      const float si = sq[gi];
      float rowmin = INFINITY;
#pragma unroll
      for (int n = 0; n < 4; ++n) {
        const int gj = j0 + wc * 64 + n * 16 + cl;
        float d2 = si + sqj[n] - 2.0f * acc[m][n][r];
        d2 = fmaxf(d2, 0.0f);
        if (gi == gj) d2 = INFINITY;
        rowmin = fminf(rowmin, d2);
        colmin[n] = fminf(colmin[n], d2);
      }
      rowmin = fminf(rowmin, __shfl_xor(rowmin, 1, 64));
      rowmin = fminf(rowmin, __shfl_xor(rowmin, 2, 64));
      rowmin = fminf(rowmin, __shfl_xor(rowmin, 4, 64));
      rowmin = fminf(rowmin, __shfl_xor(rowmin, 8, 64));
      if (cl == 0) atomicMin(minbits + gi, __float_as_uint(rowmin));
    }
  }
  if (ti != tj) {
#pragma unroll
    for (int n = 0; n < 4; ++n) {
      float cm = colmin[n];
      cm = fminf(cm, __shfl_xor(cm, 16, 64));
      cm = fminf(cm, __shfl_xor(cm, 32, 64));
      if (cg == 0) atomicMin(minbits + j0 + wc * 64 + n * 16 + cl, __float_as_uint(cm));
    }
  }
}

// ---------------------------------------------------------------------------
// Final: loss = -mean(log(sqrt(min_d2) + eps)), single block
// ---------------------------------------------------------------------------
__global__ __launch_bounds__(1024) void koleo_final(const unsigned int* __restrict__ minbits,
                                                    float* __restrict__ out) {
  __shared__ float wsum[16];
  float s = 0.f;
  for (int i = threadIdx.x; i < NROWS; i += 1024) {
    float d2 = __uint_as_float(minbits[i]);
    s += logf(sqrtf(d2) + 1e-8f);
  }
#pragma unroll
  for (int m = 32; m >= 1; m >>= 1) s += __shfl_xor(s, m, 64);
  const int wv = threadIdx.x >> 6, ln = threadIdx.x & 63;
  if (ln == 0) wsum[wv] = s;
  __syncthreads();
  if (wv == 0) {
    float t = (ln < 16) ? wsum[ln] : 0.f;
#pragma unroll
    for (int m = 8; m >= 1; m >>= 1) t += __shfl_xor(t, m, 64);
    if (ln == 0) out[0] = -t / (float)NROWS;
  }
}

// ---------------------------------------------------------------------------
extern "C" void kernel_launch(void* const* d_in, const int* in_sizes, int n_in,
                              void* d_out, int out_size, void* d_ws, size_t ws_size,
                              hipStream_t stream) {
  const float* X = (const float*)d_in[0];
  float* out = (float*)d_out;
  unsigned int* minbits = (unsigned int*)d_ws;                       // 32 KB
  float* sq = (float*)((char*)d_ws + NROWS * sizeof(unsigned int));  // 32 KB
  char* xbf = (char*)d_ws + 65536;                                   // 6.29 MB

  const size_t need = 65536 + PACK8B;
  if (ws_size >= need) {
    koleo_pack8<<<NROWS / 4, 256, 0, stream>>>(X, sq, minbits, xbf);
    koleo_tile8m<<<NTILES, 256, 65536, stream>>>(xbf, sq, minbits);
  } else {
    koleo_prep_fb<<<NROWS / 4, 256, 0, stream>>>(X, sq, minbits);
    koleo_tile_fb<<<NTILES, 256, 0, stream>>>(X, sq, minbits);
  }
  koleo_final<<<1, 1024, 0, stream>>>(minbits, out);
}

// Round 11
// 68.976 us; speedup vs baseline: 2.8125x; 1.7090x over previous
//
#include <hip/hip_runtime.h>
#include <hip/hip_bf16.h>
#include <math.h>

#define NROWS 8192
#define DIM   768
#define NKB   (DIM / 64)         // 12 k-chunks of 64
#define FCH   8192               // fp8 chunk: 128 rows x 64 cols = 8 KB
#define FPAN  (NKB * FCH)        // fp8 panel: 128 rows x 768 = 98304 B
#define NT128 (NROWS / 128)      // 64 row-blocks
#define NTILES (NT128 * (NT128 + 1) / 2)   // 2080 upper-tri tiles
#define PACK8B ((size_t)NT128 * FPAN)      // 6.29 MB

typedef __attribute__((ext_vector_type(4))) float  f32x4;
typedef __attribute__((ext_vector_type(8))) __bf16 bf16x8;
typedef __attribute__((ext_vector_type(4))) __bf16 bf16x4;
typedef __attribute__((ext_vector_type(2))) long   longx2;

__device__ __forceinline__ void gload_lds16(const void* g, void* l) {
  __builtin_amdgcn_global_load_lds(
      (const __attribute__((address_space(1))) void*)g,
      (__attribute__((address_space(3))) void*)l, 16, 0, 0);
}

// ---------------------------------------------------------------------------
// Kernel A (UNCHANGED from R7 — validated, 0 LDS conflicts downstream):
// fused fp8-pack + prep. One wave per row. f32 -> exact f32 sq-norm AND fp8
// e4m3 conversion (HW v_cvt_pk_fp8_f32) into INTERLEAVED chunk layout with
// the LDS swizzle PRE-APPLIED.
//   chunk(rb, kb) = 128 rows x 64 k-bytes. Within a row, k = ks*32 + g*8 + b
//   is stored at pos = g*16 + ks*8 + b, so ONE b128 read at pos=g*16 yields
//   both k-slices' MFMA fragments.
//   Swizzle: off = (r*64 + pos) ^ (((r>>1)&3)<<4).
// ---------------------------------------------------------------------------
__global__ __launch_bounds__(256) void koleo_pack8(const float* __restrict__ X,
                                                   float* __restrict__ sq,
                                                   unsigned int* __restrict__ minbits,
                                                   char* __restrict__ xbf) {
  const int row  = blockIdx.x * 4 + (threadIdx.x >> 6);
  const int lane = threadIdx.x & 63;
  const int rb = row >> 7, r = row & 127;
  const float* xr = X + (size_t)row * DIM;
  float s = 0.f;
#pragma unroll
  for (int i = 0; i < 3; ++i) {            // 768 = 3 * 64 lanes * 4 floats
    const int c0 = lane * 4 + i * 256;
    f32x4 v = *(const f32x4*)(xr + c0);
    s += v.x * v.x + v.y * v.y + v.z * v.z + v.w * v.w;
    int pk = __builtin_amdgcn_cvt_pk_fp8_f32(v.x, v.y, 0, false);
    pk     = __builtin_amdgcn_cvt_pk_fp8_f32(v.z, v.w, pk, true);
    const int kb = c0 >> 6;                // chunk index
    const int c  = c0 & 63;                // k within chunk
    const int ks = c >> 5;                 // k-slice 0..1
    const int g  = (c >> 3) & 3;           // lane-quarter group
    const int bb = c & 7;                  // byte in fragment
    const int pos = g * 16 + ks * 8 + bb;  // interleaved position
    const int off = (r * 64 + pos) ^ (((r >> 1) & 3) << 4);
    *(int*)(xbf + (size_t)rb * FPAN + (size_t)kb * FCH + off) = pk;
  }
#pragma unroll
  for (int m = 32; m >= 1; m >>= 1) s += __shfl_xor(s, m, 64);
  if (lane == 0) {
    sq[row]      = s;
    minbits[row] = 0x7F800000u;            // +inf
  }
}

// ---------------------------------------------------------------------------
// Kernel B: 128x128 upper-triangular Gram tiles in fp8. R11 change vs R7:
// T4 COUNTED-VMCNT 3-slot ring buffer (2-deep prefetch) replaces the
// vmcnt(0)-drain-per-chunk. Per iteration:
//   vmcnt(4)  [chunk t landed; 4 gloads/wave/chunk, FIFO-oldest m135]
//   s_barrier [all waves' chunk t visible; all waves done reading t-1]
//   issue chunk t+2 into slot (t+2)%3   [slot of t-1 -> free by barrier]
//   8x ds_read_b128 + 32 MFMA on chunk t
// Loads get ~2 compute phases of slack -> drain stall ~0.
// LDS: 3 x (A 8KB + B 8KB) = 48 KB dynamic -> 3 blocks/CU. VGPR ~64.
// Tile ordering = L2-locality segments (validated R6).
// ---------------------------------------------------------------------------
__global__ __launch_bounds__(256, 4) void koleo_tile8f(const char* __restrict__ xbf,
                                                       const float* __restrict__ sq,
                                                       unsigned int* __restrict__ minbits) {
  extern __shared__ char lds[];            // 49152 bytes (3 x 16 KB slots)

  // segment-ordered tile map
  const int b = blockIdx.x;
  int ti, tj;
  if (b < 528) {                           // T0: panels [0,32)
    int rem = b, rl = 32; ti = 0;
    while (rem >= rl) { rem -= rl; ++ti; --rl; }
    tj = ti + rem;
  } else if (b < 1552) {                   // rect bands ti:[0,32) x tj:[32+8q,40+8q)
    const int q = (b - 528) >> 8, rr = (b - 528) & 255;
    ti = rr >> 3; tj = 32 + q * 8 + (rr & 7);
  } else {                                 // T1: panels [32,64)
    int rem = b - 1552, rl = 32; ti = 32;
    while (rem >= rl) { rem -= rl; ++ti; --rl; }
    tj = ti + rem;
  }
  const int i0 = ti * 128, j0 = tj * 128;

  const int tid  = threadIdx.x;
  const int lane = tid & 63;
  const int wave = tid >> 6;               // 0..3
  const int wr   = wave >> 1;              // row half
  const int wc   = wave & 1;               // col half
  const int g16  = (lane >> 4) * 16;       // fragment 16B group offset

  const char* pA = xbf + (size_t)ti * FPAN + wave * 1024 + lane * 16;
  const char* pB = xbf + (size_t)tj * FPAN + wave * 1024 + lane * 16;

  f32x4 acc[4][4] = {};

  // ---- prologue: issue chunks 0 and 1 (issue order = vmcnt FIFO order) ---
#pragma unroll
  for (int h = 0; h < 2; ++h) {            // chunk 0 -> slot 0
    gload_lds16(pA + h * 4096, lds +        h * 4096 + wave * 1024);
    gload_lds16(pB + h * 4096, lds + 8192 + h * 4096 + wave * 1024);
  }
#pragma unroll
  for (int h = 0; h < 2; ++h) {            // chunk 1 -> slot 1
    gload_lds16(pA + FCH + h * 4096, lds + 16384 +        h * 4096 + wave * 1024);
    gload_lds16(pB + FCH + h * 4096, lds + 16384 + 8192 + h * 4096 + wave * 1024);
  }

  // ---- main K-loop: counted vmcnt, one barrier per chunk ------------------
#pragma unroll
  for (int t = 0; t < NKB; ++t) {
    if (t + 1 < NKB) asm volatile("s_waitcnt vmcnt(4)" ::: "memory");
    else             asm volatile("s_waitcnt vmcnt(0)" ::: "memory");
    __builtin_amdgcn_s_barrier();

    if (t + 2 < NKB) {                     // issue chunk t+2 into ring slot
      char* nbuf = lds + ((t + 2) % 3) * 16384;
      const char* sA = pA + (size_t)(t + 2) * FCH;
      const char* sB = pB + (size_t)(t + 2) * FCH;
#pragma unroll
      for (int h = 0; h < 2; ++h) {
        gload_lds16(sA + h * 4096, nbuf +        h * 4096 + wave * 1024);
        gload_lds16(sB + h * 4096, nbuf + 8192 + h * 4096 + wave * 1024);
      }
    }

    const char* buf = lds + (t % 3) * 16384;
    // 8x ds_read_b128: each 16B = [ks0 frag | ks1 frag] for one row
    longx2 aP[4], bP[4];
#pragma unroll
    for (int m = 0; m < 4; ++m) {
      const int ra = wr * 64 + m * 16 + (lane & 15);
      aP[m] = *(const longx2*)(buf + ((ra * 64 + g16) ^ (((ra >> 1) & 3) << 4)));
      const int rb2 = wc * 64 + m * 16 + (lane & 15);
      bP[m] = *(const longx2*)(buf + 8192 + ((rb2 * 64 + g16) ^ (((rb2 >> 1) & 3) << 4)));
    }
#pragma unroll
    for (int ks = 0; ks < 2; ++ks)
#pragma unroll
      for (int m = 0; m < 4; ++m)
#pragma unroll
        for (int n = 0; n < 4; ++n)
          acc[m][n] = __builtin_amdgcn_mfma_f32_16x16x32_fp8_fp8(aP[m][ks], bP[n][ks], acc[m][n], 0, 0, 0);
  }

  // ---- epilogue: d2, diagonal mask, row-min + col-min, atomicMin ----------
  // C/D layout (m89, dtype-independent): col = lane&15, row = (lane>>4)*4+reg
  const int cg = lane >> 4;
  const int cl = lane & 15;
  float sqj[4], colmin[4];
#pragma unroll
  for (int n = 0; n < 4; ++n) {
    sqj[n]    = sq[j0 + wc * 64 + n * 16 + cl];
    colmin[n] = INFINITY;
  }
#pragma unroll
  for (int m = 0; m < 4; ++m) {
#pragma unroll
    for (int r = 0; r < 4; ++r) {
      const int gi = i0 + wr * 64 + m * 16 + cg * 4 + r;
      const float si = sq[gi];
      float rowmin = INFINITY;
#pragma unroll
      for (int n = 0; n < 4; ++n) {
        const int gj = j0 + wc * 64 + n * 16 + cl;
        float d2 = si + sqj[n] - 2.0f * acc[m][n][r];
        d2 = fmaxf(d2, 0.0f);
        if (gi == gj) d2 = INFINITY;
        rowmin    = fminf(rowmin, d2);
        colmin[n] = fminf(colmin[n], d2);
      }
      rowmin = fminf(rowmin, __shfl_xor(rowmin, 1, 64));
      rowmin = fminf(rowmin, __shfl_xor(rowmin, 2, 64));
      rowmin = fminf(rowmin, __shfl_xor(rowmin, 4, 64));
      rowmin = fminf(rowmin, __shfl_xor(rowmin, 8, 64));
      if (cl == 0)
        atomicMin(minbits + gi, __float_as_uint(rowmin));
    }
  }
  if (ti != tj) {
#pragma unroll
    for (int n = 0; n < 4; ++n) {
      float cm = colmin[n];
      cm = fminf(cm, __shfl_xor(cm, 16, 64));
      cm = fminf(cm, __shfl_xor(cm, 32, 64));
      if (cg == 0)
        atomicMin(minbits + j0 + wc * 64 + n * 16 + cl, __float_as_uint(cm));
    }
  }
}

// ---------------------------------------------------------------------------
// Fallback (ws too small): bf16 f32-load + in-loop cvt staging, 128^2 tiles.
// ---------------------------------------------------------------------------
__global__ __launch_bounds__(256) void koleo_prep_fb(const float* __restrict__ X,
                                                     float* __restrict__ sq,
                                                     unsigned int* __restrict__ minbits) {
  const int row  = blockIdx.x * 4 + (threadIdx.x >> 6);
  const int lane = threadIdx.x & 63;
  const float* xr = X + (size_t)row * DIM;
  float s = 0.f;
#pragma unroll
  for (int i = 0; i < 3; ++i) {
    f32x4 v = *(const f32x4*)(xr + lane * 4 + i * 256);
    s += v.x * v.x + v.y * v.y + v.z * v.z + v.w * v.w;
  }
#pragma unroll
  for (int m = 32; m >= 1; m >>= 1) s += __shfl_xor(s, m, 64);
  if (lane == 0) { sq[row] = s; minbits[row] = 0x7F800000u; }
}

__global__ __launch_bounds__(256) void koleo_tile_fb(const float* __restrict__ X,
                                                     const float* __restrict__ sq,
                                                     unsigned int* __restrict__ minbits) {
  __shared__ __align__(16) char sA[16384];
  __shared__ __align__(16) char sB[16384];
  int rem = blockIdx.x, ti = 0, rowlen = NT128;
  while (rem >= rowlen) { rem -= rowlen; ++ti; --rowlen; }
  const int tj = ti + rem;
  const int i0 = ti * 128, j0 = tj * 128;
  const int tid = threadIdx.x, lane = tid & 63, wave = tid >> 6;
  const int wr = wave >> 1, wc = wave & 1;
  f32x4 acc[4][4] = {};
  for (int k0 = 0; k0 < DIM; k0 += 64) {
    __syncthreads();
#pragma unroll
    for (int it = 0; it < 8; ++it) {
      const int idx = tid + it * 256;
      const int r = idx >> 4, c4 = idx & 15;
      f32x4 va = *(const f32x4*)(X + (size_t)(i0 + r) * DIM + k0 + c4 * 4);
      f32x4 vb = *(const f32x4*)(X + (size_t)(j0 + r) * DIM + k0 + c4 * 4);
      bf16x4 ha, hb;
      ha[0] = (__bf16)va.x; ha[1] = (__bf16)va.y; ha[2] = (__bf16)va.z; ha[3] = (__bf16)va.w;
      hb[0] = (__bf16)vb.x; hb[1] = (__bf16)vb.y; hb[2] = (__bf16)vb.z; hb[3] = (__bf16)vb.w;
      int off = (r * 128 + c4 * 8) ^ ((r & 7) << 4);
      *(bf16x4*)(sA + off) = ha;
      *(bf16x4*)(sB + off) = hb;
    }
    __syncthreads();
#pragma unroll
    for (int ks = 0; ks < 2; ++ks) {
      bf16x8 af[4], bfr[4];
#pragma unroll
      for (int m = 0; m < 4; ++m) {
        const int ra = wr * 64 + m * 16 + (lane & 15);
        af[m]  = *(const bf16x8*)(sA + ((ra * 128 + ks * 64 + (lane >> 4) * 16) ^ ((ra & 7) << 4)));
        const int rb2 = wc * 64 + m * 16 + (lane & 15);
        bfr[m] = *(const bf16x8*)(sB + ((rb2 * 128 + ks * 64 + (lane >> 4) * 16) ^ ((rb2 & 7) << 4)));
      }
#pragma unroll
      for (int m = 0; m < 4; ++m)
#pragma unroll
        for (int n = 0; n < 4; ++n)
          acc[m][n] = __builtin_amdgcn_mfma_f32_16x16x32_bf16(af[m], bfr[n], acc[m][n], 0, 0, 0);
    }
  }
  const int cg = lane >> 4, cl = lane & 15;
  float sqj[4], colmin[4];
#pragma unroll
  for (int n = 0; n < 4; ++n) { sqj[n] = sq[j0 + wc * 64 + n * 16 + cl]; colmin[n] = INFINITY; }
#pragma unroll
  for (int m = 0; m < 4; ++m) {
#pragma unroll
    for (int r = 0; r < 4; ++r) {
      const int gi = i0 + wr * 64 + m * 16 + cg * 4 + r;
      const float si = sq[gi];
      float rowmin = INFINITY;
#pragma unroll
      for (int n = 0; n < 4; ++n) {
        const int gj = j0 + wc * 64 + n * 16 + cl;
        float d2 = si + sqj[n] - 2.0f * acc[m][n][r];
        d2 = fmaxf(d2, 0.0f);
        if (gi == gj) d2 = INFINITY;
        rowmin = fminf(rowmin, d2);
        colmin[n] = fminf(colmin[n], d2);
      }
      rowmin = fminf(rowmin, __shfl_xor(rowmin, 1, 64));
      rowmin = fminf(rowmin, __shfl_xor(rowmin, 2, 64));
      rowmin = fminf(rowmin, __shfl_xor(rowmin, 4, 64));
      rowmin = fminf(rowmin, __shfl_xor(rowmin, 8, 64));
      if (cl == 0) atomicMin(minbits + gi, __float_as_uint(rowmin));
    }
  }
  if (ti != tj) {
#pragma unroll
    for (int n = 0; n < 4; ++n) {
      float cm = colmin[n];
      cm = fminf(cm, __shfl_xor(cm, 16, 64));
      cm = fminf(cm, __shfl_xor(cm, 32, 64));
      if (cg == 0) atomicMin(minbits + j0 + wc * 64 + n * 16 + cl, __float_as_uint(cm));
    }
  }
}

// ---------------------------------------------------------------------------
// Final: loss = -mean(log(sqrt(min_d2) + eps)), single block
// ---------------------------------------------------------------------------
__global__ __launch_bounds__(1024) void koleo_final(const unsigned int* __restrict__ minbits,
                                                    float* __restrict__ out) {
  __shared__ float wsum[16];
  float s = 0.f;
  for (int i = threadIdx.x; i < NROWS; i += 1024) {
    float d2 = __uint_as_float(minbits[i]);
    s += logf(sqrtf(d2) + 1e-8f);
  }
#pragma unroll
  for (int m = 32; m >= 1; m >>= 1) s += __shfl_xor(s, m, 64);
  const int wv = threadIdx.x >> 6, ln = threadIdx.x & 63;
  if (ln == 0) wsum[wv] = s;
  __syncthreads();
  if (wv == 0) {
    float t = (ln < 16) ? wsum[ln] : 0.f;
#pragma unroll
    for (int m = 8; m >= 1; m >>= 1) t += __shfl_xor(t, m, 64);
    if (ln == 0) out[0] = -t / (float)NROWS;
  }
}

// ---------------------------------------------------------------------------
extern "C" void kernel_launch(void* const* d_in, const int* in_sizes, int n_in,
                              void* d_out, int out_size, void* d_ws, size_t ws_size,
                              hipStream_t stream) {
  const float* X = (const float*)d_in[0];
  float* out = (float*)d_out;
  unsigned int* minbits = (unsigned int*)d_ws;                       // 32 KB
  float* sq = (float*)((char*)d_ws + NROWS * sizeof(unsigned int));  // 32 KB
  char* xbf = (char*)d_ws + 65536;                                   // 6.29 MB

  const size_t need = 65536 + PACK8B;
  if (ws_size >= need) {
    koleo_pack8<<<NROWS / 4, 256, 0, stream>>>(X, sq, minbits, xbf);
    koleo_tile8f<<<NTILES, 256, 49152, stream>>>(xbf, sq, minbits);
  } else {
    koleo_prep_fb<<<NROWS / 4, 256, 0, stream>>>(X, sq, minbits);
    koleo_tile_fb<<<NTILES, 256, 0, stream>>>(X, sq, minbits);
  }
  koleo_final<<<1, 1024, 0, stream>>>(minbits, out);
}